// Round 5
// baseline (1059.559 us; speedup 1.0000x reference)
//
#include <hip/hip_runtime.h>
#include <math.h>

#define BB  16
#define IDF 128
#define CDF 256
#define SL  48
#define QQ  16384   // 128*128
#define QT  64      // q-tile per block

// ws layout (floats): srcT [B][IDF][SL] | sent [B][IDF] | wsvT [IDF][IDF] (i-major)
#define WS_SRCT 0
#define WS_SENT (BB*IDF*SL)
#define WS_WSVT (WS_SENT + BB*IDF)

__global__ __launch_bounds__(256) void prep_kernel(
    const float* __restrict__ context,   // [B][CDF][SL]
    const float* __restrict__ w_ctx,     // [IDF][CDF]
    const float* __restrict__ sentence,  // [B][100]
    const float* __restrict__ w_lin,     // [IDF][100]
    const float* __restrict__ b_lin,     // [IDF]
    const float* __restrict__ w_sv,      // [IDF][IDF] (o,i)
    float* __restrict__ srcT,            // [B][IDF][SL]
    float* __restrict__ sent,            // [B][IDF]
    float* __restrict__ wsvT)            // [IDF][IDF] (i,o)
{
    const int b    = blockIdx.x;
    const int iblk = blockIdx.y;       // 0..3, 32 output rows each
    const int t    = threadIdx.x;

    __shared__ float ctx_lds[CDF * SL];   // 48 KB
    __shared__ float w_lds[32 * CDF];     // 32 KB

    {
        const float4* g4 = (const float4*)(context + b * CDF * SL);
        float4* s4 = (float4*)ctx_lds;
        #pragma unroll
        for (int r = 0; r < (CDF * SL) / 1024; ++r)
            s4[r * 256 + t] = g4[r * 256 + t];
    }
    const int i0 = iblk * 32;
    {
        const float4* g4 = (const float4*)(w_ctx + i0 * CDF);
        float4* s4 = (float4*)w_lds;
        #pragma unroll
        for (int r = 0; r < (32 * CDF) / 1024; ++r)
            s4[r * 256 + t] = g4[r * 256 + t];
    }
    __syncthreads();

    for (int r = 0; r < 6; ++r) {
        int idx = r * 256 + t;          // 0..1535
        int ii = idx / SL, s = idx % SL;
        float a0 = 0.f, a1 = 0.f, a2 = 0.f, a3 = 0.f;
        for (int c = 0; c < CDF; c += 4) {
            a0 += w_lds[ii * CDF + c + 0] * ctx_lds[(c + 0) * SL + s];
            a1 += w_lds[ii * CDF + c + 1] * ctx_lds[(c + 1) * SL + s];
            a2 += w_lds[ii * CDF + c + 2] * ctx_lds[(c + 2) * SL + s];
            a3 += w_lds[ii * CDF + c + 3] * ctx_lds[(c + 3) * SL + s];
        }
        srcT[(b * IDF + i0 + ii) * SL + s] = (a0 + a1) + (a2 + a3);
    }

    if (t < 32) {
        int o = iblk * 32 + t;
        float a = b_lin[o];
        for (int k = 0; k < 100; ++k)
            a += sentence[b * 100 + k] * w_lin[o * 100 + k];
        sent[b * IDF + o] = a;
    }

    if (b == 0) {
        for (int r = 0; r < 16; ++r) {
            int idx = iblk * 4096 + r * 256 + t;
            int i = idx >> 7, o = idx & 127;
            wsvT[idx] = w_sv[o * IDF + i];
        }
    }
}

// Fused kernel. Phases A (sentence GEMV) and B (logits) share ONE i-loop so
// each lgkmcnt(0) stall point is covered by 45 FMAs. att_lds aliases xs
// (xs is dead after the merged loop) -> 34.5 KB LDS -> 4 blocks/CU.
__global__ __launch_bounds__(256, 4) void fused_kernel(
    const float* __restrict__ input,   // [B][IDF][Q]
    const float* __restrict__ srcT,    // [B][IDF][SL]
    const float* __restrict__ wsvT,    // [IDF(i)][IDF(o)]
    const float* __restrict__ sentW,   // [B][IDF]
    const int*   __restrict__ mask,    // [B][SL]
    float* __restrict__ wctx,          // out0 [B][IDF][Q]
    float* __restrict__ wsent,         // out1 [B][IDF][Q]
    float* __restrict__ wattn,         // out2 [B][SL][Q]
    float* __restrict__ satt)          // out3 [B][IDF][Q]
{
    const int bid  = blockIdx.x;          // 4096 = 16 b x 256 tiles
    const int b    = bid >> 8;
    const int q0   = (bid & 255) * QT;
    const int t    = threadIdx.x;
    const int wave = __builtin_amdgcn_readfirstlane(t >> 6);  // 0..3
    const int lane = t & 63;

    __shared__ float xs[IDF * QT];        // 32 KB [i][q]; later aliased as att[SL][QT]
    __shared__ float red_m[4][QT];
    __shared__ float red_s[4][QT];
    __shared__ float sbias[SL];

    // ---- stage input tile (2048 float4, 8 per thread) ----
    {
        float4* s4 = (float4*)xs;
        #pragma unroll
        for (int r = 0; r < 8; ++r) {
            int idx = r * 256 + t;         // float4 index 0..2047
            int i = idx >> 4, c = idx & 15;
            s4[idx] = *(const float4*)(input + ((size_t)b * IDF + i) * QQ + q0 + c * 4);
        }
    }
    if (t < SL) sbias[t] = mask[b * SL + t] ? -INFINITY : 0.f;
    __syncthreads();

    const float* sT = srcT + b * IDF * SL;       // block-uniform
    const float* wA = wsvT + wave * 32;          // wave-uniform
    const float* sw = sentW + b * IDF;           // block-uniform
    const int s0 = wave * 12;

    //======== merged i-loop: phase B logits (12) + phase A GEMV (32) ========
    float l[12];
    float acc[32];
    #pragma unroll
    for (int j = 0; j < 12; ++j) l[j] = 0.f;
    #pragma unroll
    for (int oo = 0; oo < 32; ++oo) acc[oo] = 0.f;

    for (int i = 0; i < IDF; ++i) {
        float x = xs[i * QT + lane];                           // ds_read_b32
        const float4* rB = (const float4*)(sT + i * SL + s0);  // uniform -> s_load
        float4 b0 = rB[0], b1 = rB[1], b2 = rB[2];
        const float4* rA = (const float4*)(wA + i * IDF);      // uniform -> s_load
        float v = x * sw[i];

        l[0]  += x * b0.x;  l[1]  += x * b0.y;  l[2]  += x * b0.z;  l[3]  += x * b0.w;
        l[4]  += x * b1.x;  l[5]  += x * b1.y;  l[6]  += x * b1.z;  l[7]  += x * b1.w;
        l[8]  += x * b2.x;  l[9]  += x * b2.y;  l[10] += x * b2.z;  l[11] += x * b2.w;

        #pragma unroll
        for (int jj = 0; jj < 8; ++jj) {
            float4 w = rA[jj];
            acc[jj * 4 + 0] += w.x * v;
            acc[jj * 4 + 1] += w.y * v;
            acc[jj * 4 + 2] += w.z * v;
            acc[jj * 4 + 3] += w.w * v;
        }
    }

    //======== phase B softmax (cross-wave over s) ========
    float mloc = -INFINITY;
    #pragma unroll
    for (int j = 0; j < 12; ++j) {
        l[j] += sbias[s0 + j];
        mloc = fmaxf(mloc, l[j]);
    }
    red_m[wave][lane] = mloc;
    __syncthreads();                     // also: every wave is done reading xs
    float mq = fmaxf(fmaxf(red_m[0][lane], red_m[1][lane]),
                     fmaxf(red_m[2][lane], red_m[3][lane]));
    float sloc = 0.f;
    #pragma unroll
    for (int j = 0; j < 12; ++j) { l[j] = __expf(l[j] - mq); sloc += l[j]; }
    red_s[wave][lane] = sloc;
    __syncthreads();
    float tot = (red_s[0][lane] + red_s[1][lane]) + (red_s[2][lane] + red_s[3][lane]);
    float inv = 1.f / tot;

    float* att_s = xs;                   // alias: xs dead, reuse as att[SL][QT]
    #pragma unroll
    for (int j = 0; j < 12; ++j) {
        float a = l[j] * inv;
        wattn[((size_t)b * SL + s0 + j) * QQ + q0 + lane] = a;
        att_s[(s0 + j) * QT + lane] = a;
    }
    __syncthreads();

    //======== phase C: wctx (wave owns 32 i) ========
    {
        float att[SL];
        #pragma unroll
        for (int s = 0; s < SL; ++s) att[s] = att_s[s * QT + lane];
        const int i0c = wave * 32;
        for (int ii = 0; ii < 32; ++ii) {
            int i = i0c + ii;
            const float4* r4 = (const float4*)(sT + i * SL);   // uniform -> s_load
            float p0 = 0.f, p1 = 0.f, p2 = 0.f, p3 = 0.f;
            #pragma unroll
            for (int jj = 0; jj < 12; ++jj) {
                float4 w = r4[jj];
                p0 += w.x * att[jj * 4 + 0];
                p1 += w.y * att[jj * 4 + 1];
                p2 += w.z * att[jj * 4 + 2];
                p3 += w.w * att[jj * 4 + 3];
            }
            wctx[((size_t)b * IDF + i) * QQ + q0 + lane] = (p0 + p1) + (p2 + p3);
        }
    }

    //======== phase A softmax (cross-wave over channels) + stores ========
    {
        float lmax = -INFINITY;
        #pragma unroll
        for (int oo = 0; oo < 32; ++oo) lmax = fmaxf(lmax, acc[oo]);
        red_m[wave][lane] = lmax;
        __syncthreads();
        float mc = fmaxf(fmaxf(red_m[0][lane], red_m[1][lane]),
                         fmaxf(red_m[2][lane], red_m[3][lane]));
        float lsum = 0.f;
        #pragma unroll
        for (int oo = 0; oo < 32; ++oo) { acc[oo] = __expf(acc[oo] - mc); lsum += acc[oo]; }
        red_s[wave][lane] = lsum;
        __syncthreads();
        float ctot = (red_s[0][lane] + red_s[1][lane]) + (red_s[2][lane] + red_s[3][lane]);
        float cinv = 1.f / ctot;

        #pragma unroll
        for (int oo = 0; oo < 32; ++oo) {
            int o = wave * 32 + oo;
            float p = acc[oo] * cinv;
            size_t off = ((size_t)b * IDF + o) * QQ + q0 + lane;
            satt[off]  = p;
            wsent[off] = sw[o] * p;
        }
    }
}

extern "C" void kernel_launch(void* const* d_in, const int* in_sizes, int n_in,
                              void* d_out, int out_size, void* d_ws, size_t ws_size,
                              hipStream_t stream) {
    const float* input    = (const float*)d_in[0];
    const float* sentence = (const float*)d_in[1];
    const float* context  = (const float*)d_in[2];
    const int*   mask     = (const int*)d_in[3];
    const float* w_ctx    = (const float*)d_in[4];
    const float* w_sv     = (const float*)d_in[5];
    const float* w_lin    = (const float*)d_in[6];
    const float* b_lin    = (const float*)d_in[7];

    float* out = (float*)d_out;
    float* out_wctx  = out;                                   // [B][IDF][Q]
    float* out_wsent = out + (size_t)BB * IDF * QQ;           // [B][IDF][Q]
    float* out_wattn = out + 2 * (size_t)BB * IDF * QQ;       // [B][SL][Q]
    float* out_satt  = out_wattn + (size_t)BB * SL * QQ;      // [B][IDF][Q]

    float* ws   = (float*)d_ws;
    float* srcT = ws + WS_SRCT;
    float* sent = ws + WS_SENT;
    float* wsvT = ws + WS_WSVT;

    prep_kernel<<<dim3(16, 4), 256, 0, stream>>>(context, w_ctx, sentence,
                                                 w_lin, b_lin, w_sv,
                                                 srcT, sent, wsvT);
    fused_kernel<<<dim3(4096), 256, 0, stream>>>(input, srcT, wsvT, sent, mask,
                                                 out_wctx, out_wsent,
                                                 out_wattn, out_satt);
}

// Round 6
// 669.977 us; speedup vs baseline: 1.5815x; 1.5815x over previous
//
#include <hip/hip_runtime.h>
#include <math.h>

#define BB  16
#define IDF 128
#define CDF 256
#define SL  48
#define QQ  16384   // 128*128
#define QT  64      // q-tile per block

// ws layout (floats): srcT [B][IDF][SL] | sent [B][IDF] | wsvT [IDF][IDF] (i-major)
#define WS_SRCT 0
#define WS_SENT (BB*IDF*SL)
#define WS_WSVT (WS_SENT + BB*IDF)

__global__ __launch_bounds__(256) void prep_kernel(
    const float* __restrict__ context,   // [B][CDF][SL]
    const float* __restrict__ w_ctx,     // [IDF][CDF]
    const float* __restrict__ sentence,  // [B][100]
    const float* __restrict__ w_lin,     // [IDF][100]
    const float* __restrict__ b_lin,     // [IDF]
    const float* __restrict__ w_sv,      // [IDF][IDF] (o,i)
    float* __restrict__ srcT,            // [B][IDF][SL]
    float* __restrict__ sent,            // [B][IDF]
    float* __restrict__ wsvT)            // [IDF][IDF] (i,o)
{
    const int b    = blockIdx.x;
    const int iblk = blockIdx.y;       // 0..3, 32 output rows each
    const int t    = threadIdx.x;

    __shared__ float ctx_lds[CDF * SL];   // 48 KB
    __shared__ float w_lds[32 * CDF];     // 32 KB

    {
        const float4* g4 = (const float4*)(context + b * CDF * SL);
        float4* s4 = (float4*)ctx_lds;
        #pragma unroll
        for (int r = 0; r < (CDF * SL) / 1024; ++r)
            s4[r * 256 + t] = g4[r * 256 + t];
    }
    const int i0 = iblk * 32;
    {
        const float4* g4 = (const float4*)(w_ctx + i0 * CDF);
        float4* s4 = (float4*)w_lds;
        #pragma unroll
        for (int r = 0; r < (32 * CDF) / 1024; ++r)
            s4[r * 256 + t] = g4[r * 256 + t];
    }
    __syncthreads();

    for (int r = 0; r < 6; ++r) {
        int idx = r * 256 + t;          // 0..1535
        int ii = idx / SL, s = idx % SL;
        float a0 = 0.f, a1 = 0.f, a2 = 0.f, a3 = 0.f;
        for (int c = 0; c < CDF; c += 4) {
            a0 += w_lds[ii * CDF + c + 0] * ctx_lds[(c + 0) * SL + s];
            a1 += w_lds[ii * CDF + c + 1] * ctx_lds[(c + 1) * SL + s];
            a2 += w_lds[ii * CDF + c + 2] * ctx_lds[(c + 2) * SL + s];
            a3 += w_lds[ii * CDF + c + 3] * ctx_lds[(c + 3) * SL + s];
        }
        srcT[(b * IDF + i0 + ii) * SL + s] = (a0 + a1) + (a2 + a3);
    }

    if (t < 32) {
        int o = iblk * 32 + t;
        float a = b_lin[o];
        for (int k = 0; k < 100; ++k)
            a += sentence[b * 100 + k] * w_lin[o * 100 + k];
        sent[b * IDF + o] = a;
    }

    if (b == 0) {
        for (int r = 0; r < 16; ++r) {
            int idx = iblk * 4096 + r * 256 + t;
            int i = idx >> 7, o = idx & 127;
            wsvT[idx] = w_sv[o * IDF + i];
        }
    }
}

// Fused kernel, stall-dense structure:
//  - merged i-loop (logits 12 FMA + sentence GEMV 32 FMA) with x pre-chunked
//    into VGPRs so the hot loop is pure s_load+FMA (one lgkmcnt drain per i,
//    45 FMAs of cover, 4 waves/SIMD -> latency hidden)
//  - A-softmax/stores BEFORE phase C so acc[32] dies before att[48] loads
__global__ __launch_bounds__(256, 4) void fused_kernel(
    const float* __restrict__ input,   // [B][IDF][Q]
    const float* __restrict__ srcT,    // [B][IDF][SL]
    const float* __restrict__ wsvT,    // [IDF(i)][IDF(o)]
    const float* __restrict__ sentW,   // [B][IDF]
    const int*   __restrict__ mask,    // [B][SL]
    float* __restrict__ wctx,          // out0 [B][IDF][Q]
    float* __restrict__ wsent,         // out1 [B][IDF][Q]
    float* __restrict__ wattn,         // out2 [B][SL][Q]
    float* __restrict__ satt)          // out3 [B][IDF][Q]
{
    const int bid  = blockIdx.x;          // 4096 = 16 b x 256 tiles
    const int b    = bid >> 8;
    const int q0   = (bid & 255) * QT;
    const int t    = threadIdx.x;
    const int wave = __builtin_amdgcn_readfirstlane(t >> 6);  // 0..3
    const int lane = t & 63;

    __shared__ float xs[IDF * QT];        // 32 KB [i][q]; aliased as att[SL][QT] later
    __shared__ float red_m[4][QT];
    __shared__ float red_s[4][QT];
    __shared__ float sbias[SL];

    // ---- stage input tile (2048 float4, 8 per thread) ----
    {
        float4* s4 = (float4*)xs;
        #pragma unroll
        for (int r = 0; r < 8; ++r) {
            int idx = r * 256 + t;         // float4 index 0..2047
            int i = idx >> 4, c = idx & 15;
            s4[idx] = *(const float4*)(input + ((size_t)b * IDF + i) * QQ + q0 + c * 4);
        }
    }
    if (t < SL) sbias[t] = mask[b * SL + t] ? -INFINITY : 0.f;
    __syncthreads();

    const float* sT = srcT + b * IDF * SL;       // block-uniform
    const float* wA = wsvT + wave * 32;          // wave-uniform
    const float* sw = sentW + b * IDF;           // block-uniform
    const int s0 = wave * 12;

    //======== merged i-loop: logits l[12] + sentence GEMV acc[32] ========
    float l[12];
    float acc[32];
    #pragma unroll
    for (int j = 0; j < 12; ++j) l[j] = 0.f;
    #pragma unroll
    for (int oo = 0; oo < 32; ++oo) acc[oo] = 0.f;

    for (int ic = 0; ic < 4; ++ic) {              // NOT unrolled (I$)
        // preload this chunk's x into registers: one LDS drain per 32 i
        float xr[32];
        #pragma unroll
        for (int k = 0; k < 32; ++k)
            xr[k] = xs[(ic * 32 + k) * QT + lane];

        // pure s_load + FMA loop (no ds_read -> no forced full drains
        // beyond the per-iter SMEM wait, covered by 45 FMAs x 4 waves/SIMD)
        #pragma unroll
        for (int k = 0; k < 32; ++k) {
            const int i = ic * 32 + k;
            const float4* rB = (const float4*)(sT + i * SL + s0);  // s_load x3
            const float4* rA = (const float4*)(wA + i * IDF);      // s_load x8
            float4 w0 = rB[0], w1 = rB[1], w2 = rB[2];
            float x = xr[k];
            float v = x * sw[i];

            l[0]  += x * w0.x;  l[1]  += x * w0.y;  l[2]  += x * w0.z;  l[3]  += x * w0.w;
            l[4]  += x * w1.x;  l[5]  += x * w1.y;  l[6]  += x * w1.z;  l[7]  += x * w1.w;
            l[8]  += x * w2.x;  l[9]  += x * w2.y;  l[10] += x * w2.z;  l[11] += x * w2.w;

            #pragma unroll
            for (int jj = 0; jj < 8; ++jj) {
                float4 w = rA[jj];
                acc[jj * 4 + 0] += w.x * v;
                acc[jj * 4 + 1] += w.y * v;
                acc[jj * 4 + 2] += w.z * v;
                acc[jj * 4 + 3] += w.w * v;
            }
        }
    }

    //======== phase B softmax (cross-wave over s) -> att_lds + wattn ========
    float mloc = -INFINITY;
    #pragma unroll
    for (int j = 0; j < 12; ++j) {
        l[j] += sbias[s0 + j];
        mloc = fmaxf(mloc, l[j]);
    }
    red_m[wave][lane] = mloc;
    __syncthreads();                   // all waves done with merged loop + xs
    float mq = fmaxf(fmaxf(red_m[0][lane], red_m[1][lane]),
                     fmaxf(red_m[2][lane], red_m[3][lane]));
    float sloc = 0.f;
    #pragma unroll
    for (int j = 0; j < 12; ++j) { l[j] = __expf(l[j] - mq); sloc += l[j]; }
    red_s[wave][lane] = sloc;
    __syncthreads();
    float tot = (red_s[0][lane] + red_s[1][lane]) + (red_s[2][lane] + red_s[3][lane]);
    float inv = 1.f / tot;

    float* att_s = xs;                 // alias: xs dead, reuse as att[SL][QT]
    #pragma unroll
    for (int j = 0; j < 12; ++j) {
        float a = l[j] * inv;
        wattn[((size_t)b * SL + s0 + j) * QQ + q0 + lane] = a;
        att_s[(s0 + j) * QT + lane] = a;
    }

    //======== phase A softmax (cross-wave over channels) + stores ========
    // (before phase C so acc[32] dies before att[48] is loaded)
    {
        float lmax = -INFINITY;
        #pragma unroll
        for (int oo = 0; oo < 32; ++oo) lmax = fmaxf(lmax, acc[oo]);
        red_m[wave][lane] = lmax;      // safe: red_m reads finished before bar2
        __syncthreads();               // bar3: also publishes att_s
        float mc = fmaxf(fmaxf(red_m[0][lane], red_m[1][lane]),
                         fmaxf(red_m[2][lane], red_m[3][lane]));
        float lsum = 0.f;
        #pragma unroll
        for (int oo = 0; oo < 32; ++oo) { acc[oo] = __expf(acc[oo] - mc); lsum += acc[oo]; }
        red_s[wave][lane] = lsum;
        __syncthreads();               // bar4
        float ctot = (red_s[0][lane] + red_s[1][lane]) + (red_s[2][lane] + red_s[3][lane]);
        float cinv = 1.f / ctot;

        #pragma unroll
        for (int oo = 0; oo < 32; ++oo) {
            int o = wave * 32 + oo;
            float p = acc[oo] * cinv;
            size_t off = ((size_t)b * IDF + o) * QQ + q0 + lane;
            satt[off]  = p;
            wsent[off] = sw[o] * p;
        }
    }

    //======== phase C: wctx (wave owns 32 i), pure s_load + FMA ========
    {
        float att[SL];
        #pragma unroll
        for (int s = 0; s < SL; ++s) att[s] = att_s[s * QT + lane];
        const int i0c = wave * 32;
        for (int ii = 0; ii < 32; ++ii) {
            int i = i0c + ii;
            const float4* r4 = (const float4*)(sT + i * SL);   // s_load x12
            float p0 = 0.f, p1 = 0.f, p2 = 0.f, p3 = 0.f;
            #pragma unroll
            for (int jj = 0; jj < 12; ++jj) {
                float4 w = r4[jj];
                p0 += w.x * att[jj * 4 + 0];
                p1 += w.y * att[jj * 4 + 1];
                p2 += w.z * att[jj * 4 + 2];
                p3 += w.w * att[jj * 4 + 3];
            }
            wctx[((size_t)b * IDF + i) * QQ + q0 + lane] = (p0 + p1) + (p2 + p3);
        }
    }
}

extern "C" void kernel_launch(void* const* d_in, const int* in_sizes, int n_in,
                              void* d_out, int out_size, void* d_ws, size_t ws_size,
                              hipStream_t stream) {
    const float* input    = (const float*)d_in[0];
    const float* sentence = (const float*)d_in[1];
    const float* context  = (const float*)d_in[2];
    const int*   mask     = (const int*)d_in[3];
    const float* w_ctx    = (const float*)d_in[4];
    const float* w_sv     = (const float*)d_in[5];
    const float* w_lin    = (const float*)d_in[6];
    const float* b_lin    = (const float*)d_in[7];

    float* out = (float*)d_out;
    float* out_wctx  = out;                                   // [B][IDF][Q]
    float* out_wsent = out + (size_t)BB * IDF * QQ;           // [B][IDF][Q]
    float* out_wattn = out + 2 * (size_t)BB * IDF * QQ;       // [B][SL][Q]
    float* out_satt  = out_wattn + (size_t)BB * SL * QQ;      // [B][IDF][Q]

    float* ws   = (float*)d_ws;
    float* srcT = ws + WS_SRCT;
    float* sent = ws + WS_SENT;
    float* wsvT = ws + WS_WSVT;

    prep_kernel<<<dim3(16, 4), 256, 0, stream>>>(context, w_ctx, sentence,
                                                 w_lin, b_lin, w_sv,
                                                 srcT, sent, wsvT);
    fused_kernel<<<dim3(4096), 256, 0, stream>>>(input, srcT, wsvT, sent, mask,
                                                 out_wctx, out_wsent,
                                                 out_wattn, out_satt);
}

// Round 8
// 228.701 us; speedup vs baseline: 4.6330x; 2.9295x over previous
//
#include <hip/hip_runtime.h>
#include <math.h>
#include <stdint.h>

#define BB  16
#define IDF 128
#define CDF 256
#define SL  48
#define QQ  16384   // 128*128
#define QT  64      // q-tile per block

typedef short bf16x8 __attribute__((ext_vector_type(8)));
typedef short bf16x4 __attribute__((ext_vector_type(4)));
typedef float f32x4  __attribute__((ext_vector_type(4)));

__device__ __forceinline__ short f2bf(float f) {
    uint32_t u = __builtin_bit_cast(uint32_t, f);
    u += 0x7FFFu + ((u >> 16) & 1u);          // RNE
    return (short)(u >> 16);
}
__device__ __forceinline__ float bf2f(short h) {
    uint32_t u = ((uint32_t)(unsigned short)h) << 16;
    return __builtin_bit_cast(float, u);
}

// ===================== prep: srcT (f32) + sent =====================
__global__ __launch_bounds__(256) void prep_kernel(
    const float* __restrict__ context,   // [B][CDF][SL]
    const float* __restrict__ w_ctx,     // [IDF][CDF]
    const float* __restrict__ sentence,  // [B][100]
    const float* __restrict__ w_lin,     // [IDF][100]
    const float* __restrict__ b_lin,     // [IDF]
    float* __restrict__ srcT,            // [B][IDF][SL]
    float* __restrict__ sent)            // [B][IDF]
{
    const int b    = blockIdx.x;
    const int iblk = blockIdx.y;
    const int t    = threadIdx.x;

    __shared__ float ctx_lds[CDF * SL];   // 48 KB
    __shared__ float w_lds[32 * CDF];     // 32 KB

    {
        const float4* g4 = (const float4*)(context + b * CDF * SL);
        float4* s4 = (float4*)ctx_lds;
        #pragma unroll
        for (int r = 0; r < (CDF * SL) / 1024; ++r)
            s4[r * 256 + t] = g4[r * 256 + t];
    }
    const int i0 = iblk * 32;
    {
        const float4* g4 = (const float4*)(w_ctx + i0 * CDF);
        float4* s4 = (float4*)w_lds;
        #pragma unroll
        for (int r = 0; r < (32 * CDF) / 1024; ++r)
            s4[r * 256 + t] = g4[r * 256 + t];
    }
    __syncthreads();

    for (int r = 0; r < 6; ++r) {
        int idx = r * 256 + t;
        int ii = idx / SL, s = idx % SL;
        float a0 = 0.f, a1 = 0.f, a2 = 0.f, a3 = 0.f;
        for (int cc = 0; cc < CDF; cc += 4) {
            a0 += w_lds[ii * CDF + cc + 0] * ctx_lds[(cc + 0) * SL + s];
            a1 += w_lds[ii * CDF + cc + 1] * ctx_lds[(cc + 1) * SL + s];
            a2 += w_lds[ii * CDF + cc + 2] * ctx_lds[(cc + 2) * SL + s];
            a3 += w_lds[ii * CDF + cc + 3] * ctx_lds[(cc + 3) * SL + s];
        }
        srcT[(b * IDF + i0 + ii) * SL + s] = (a0 + a1) + (a2 + a3);
    }

    if (t < 32) {
        int o = iblk * 32 + t;
        float a = b_lin[o];
        for (int k = 0; k < 100; ++k)
            a += sentence[b * 100 + k] * w_lin[o * 100 + k];
        sent[b * IDF + o] = a;
    }
}

// ============ prep2: fragment-ordered bf16 A-operand arrays ============
// A-frag map (verified m97 combo): lane l=(c=l&15, g=l>>4), elem j ->
// A[m = c + 16*Mt][k = 8*g + 32*ks + j]. Any k-permutation error cancels
// because B-frags use the identical slot map.
__global__ __launch_bounds__(256) void prep2_kernel(
    const float* __restrict__ srcT,   // [B][128][48]
    const float* __restrict__ sentW,  // [B][128]
    const float* __restrict__ w_sv,   // [128 o][128 i]
    short* __restrict__ wsvS,         // [B][8Mt][4ks][64][8]   (w_sv*sent)
    short* __restrict__ stB,          // [B][3Mt][4ks][2(hi,lo)][64][8] (srcT^T)
    short* __restrict__ stC)          // [B][8Mt][2ks][64][8]   (srcT, s pad 64)
{
    const int b = blockIdx.x;
    const int part = blockIdx.y;
    const int t = threadIdx.x;
    const int wv = t >> 6, l = t & 63;
    const int c = l & 15, g = l >> 4;

    if (part == 0) {
        #pragma unroll
        for (int cc = 0; cc < 8; ++cc) {
            int comb = wv * 8 + cc;           // 0..31
            int Mt = comb >> 2, ks = comb & 3;
            int o = c + 16 * Mt;
            int ib = g * 8 + 32 * ks;
            bf16x8 outv;
            #pragma unroll
            for (int j = 0; j < 8; ++j)
                outv[j] = f2bf(w_sv[o * IDF + ib + j] * sentW[b * IDF + ib + j]);
            *(bf16x8*)(wsvS + (size_t)b * 16384 + ((Mt * 4 + ks) * 64 + l) * 8) = outv;
        }
    } else if (part == 1) {
        #pragma unroll
        for (int cc = 0; cc < 3; ++cc) {
            int comb = wv * 3 + cc;           // 0..11
            int Mt = comb >> 2, ks = comb & 3;
            int s = c + 16 * Mt;
            int ib = g * 8 + 32 * ks;
            bf16x8 hv, lv;
            #pragma unroll
            for (int j = 0; j < 8; ++j) {
                float v = srcT[((size_t)b * IDF + ib + j) * SL + s];
                short h = f2bf(v);
                hv[j] = h;
                lv[j] = f2bf(v - bf2f(h));
            }
            size_t base = (size_t)b * 12288 + (((Mt * 4 + ks) * 2) * 64 + l) * 8;
            *(bf16x8*)(stB + base) = hv;
            *(bf16x8*)(stB + base + 64 * 8) = lv;
        }
    } else {
        #pragma unroll
        for (int cc = 0; cc < 4; ++cc) {
            int comb = wv * 4 + cc;           // 0..15
            int Mt = comb >> 1, ks = comb & 1;
            int i = c + 16 * Mt;
            int sb = g * 8 + 32 * ks;
            bf16x8 v8;
            #pragma unroll
            for (int j = 0; j < 8; ++j) {
                int s = sb + j;
                v8[j] = (s < SL) ? f2bf(srcT[((size_t)b * IDF + i) * SL + s])
                                 : (short)0;
            }
            *(bf16x8*)(stC + (size_t)b * 8192 + ((Mt * 2 + ks) * 64 + l) * 8) = v8;
        }
    }
}

// ===================== fused MFMA kernel =====================
// B-operands (per-q data) live in LDS TRANSPOSED: xq[q][i] / attq[q][s],
// XOR-swizzled 16B chunks, so every fragment is a plain ds_read_b128 of
// 8 k-contiguous bf16 (no tr-read, no layout unknowns).
__global__ __launch_bounds__(256) void fused_kernel(
    const float* __restrict__ input,   // [B][IDF][Q]
    const short* __restrict__ stB,
    const short* __restrict__ stC,
    const short* __restrict__ wsvS,
    const float* __restrict__ sentW,   // [B][IDF]
    const int*   __restrict__ mask,    // [B][SL]
    float* __restrict__ wctx, float* __restrict__ wsent,
    float* __restrict__ wattn, float* __restrict__ satt)
{
    const int bid = blockIdx.x;           // 4096 = 16 b x 256 tiles
    const int b   = bid >> 8;
    const int q0  = (bid & 255) * QT;
    const int t   = threadIdx.x;
    const int w   = t >> 6;               // wave -> q-strip (16 q)
    const int l   = t & 63;
    const int c   = l & 15;
    const int g   = l >> 4;

    __shared__ __align__(16) short xqh[QT * IDF];    // 16 KB [q][i^swz] hi
    __shared__ __align__(16) short xql[QT * IDF];    // 16 KB lo
    __shared__ __align__(16) short attq[4 * 16 * 64];// 8 KB [strip][q][s^swz]
    __shared__ float sbias[SL];
    __shared__ float sent_lds[IDF];

    // zero attq (s pad rows 48..63 must be 0)
    {
        bf16x8 z = {0, 0, 0, 0, 0, 0, 0, 0};
        *(bf16x8*)(attq + t * 16) = z;
        *(bf16x8*)(attq + t * 16 + 8) = z;
    }

    // ---- stage x transposed, hi/lo split ----
    {
        const int qb = (t & 15) * 4;
        #pragma unroll
        for (int r = 0; r < 4; ++r) {
            int i = (r * 16 + (t >> 4)) * 2;
            const float4 va = *(const float4*)(input + ((size_t)b * IDF + i    ) * QQ + q0 + qb);
            const float4 vb = *(const float4*)(input + ((size_t)b * IDF + i + 1) * QQ + q0 + qb);
            float va_[4] = {va.x, va.y, va.z, va.w};
            float vb_[4] = {vb.x, vb.y, vb.z, vb.w};
            #pragma unroll
            for (int jj = 0; jj < 4; ++jj) {
                int q = qb + jj;
                short h0 = f2bf(va_[jj]);
                short h1 = f2bf(vb_[jj]);
                short l0 = f2bf(va_[jj] - bf2f(h0));
                short l1 = f2bf(vb_[jj] - bf2f(h1));
                int e = q * IDF + (i ^ ((q & 15) << 3));   // i even -> e even
                *(uint32_t*)(xqh + e) = (uint32_t)(uint16_t)h0 | ((uint32_t)(uint16_t)h1 << 16);
                *(uint32_t*)(xql + e) = (uint32_t)(uint16_t)l0 | ((uint32_t)(uint16_t)l1 << 16);
            }
        }
    }
    if (t < SL)  sbias[t] = mask[b * SL + t] ? -INFINITY : 0.f;
    if (t < IDF) sent_lds[t] = sentW[b * IDF + t];
    __syncthreads();   // the ONLY barrier; afterwards wave w owns its strip

    // ---- x B-fragments: plain b128, k = 32*ks + 8*g + j, n(q-col) = c ----
    const int qrow = 16 * w + c;
    const short* xh_p = xqh + qrow * IDF;
    const short* xl_p = xql + qrow * IDF;
    bf16x8 fxh[4], fxl[4];
    #pragma unroll
    for (int ks = 0; ks < 4; ++ks) {
        int off = (32 * ks + 8 * g) ^ (c << 3);   // qrow&15 == c
        fxh[ks] = *(const bf16x8*)(xh_p + off);
        fxl[ks] = *(const bf16x8*)(xl_p + off);
    }

    const int q = q0 + qrow;

    // ======== phase B: logits L[s][q] = srcT^T x (hi/lo split) ========
    const short* stBb = stB + (size_t)b * 12288;
    f32x4 accB[3];
    #pragma unroll
    for (int Mt = 0; Mt < 3; ++Mt) {
        f32x4 a = {0.f, 0.f, 0.f, 0.f};
        #pragma unroll
        for (int ks = 0; ks < 4; ++ks) {
            const bf16x8 sh = *(const bf16x8*)(stBb + ((((Mt * 4 + ks) * 2 + 0) * 64 + l) * 8));
            const bf16x8 sl = *(const bf16x8*)(stBb + ((((Mt * 4 + ks) * 2 + 1) * 64 + l) * 8));
            a = __builtin_amdgcn_mfma_f32_16x16x32_bf16(sh, fxh[ks], a, 0, 0, 0);
            a = __builtin_amdgcn_mfma_f32_16x16x32_bf16(sh, fxl[ks], a, 0, 0, 0);
            a = __builtin_amdgcn_mfma_f32_16x16x32_bf16(sl, fxh[ks], a, 0, 0, 0);
        }
        accB[Mt] = a;
    }

    // softmax over s per q (q = col = c; s spread over g and regs)
    float mx = -INFINITY;
    #pragma unroll
    for (int Mt = 0; Mt < 3; ++Mt)
        #pragma unroll
        for (int r = 0; r < 4; ++r) {
            int s = 16 * Mt + 4 * g + r;
            float lv = accB[Mt][r] + sbias[s];
            accB[Mt][r] = lv;
            mx = fmaxf(mx, lv);
        }
    mx = fmaxf(mx, __shfl_xor(mx, 16));
    mx = fmaxf(mx, __shfl_xor(mx, 32));
    float sum = 0.f;
    #pragma unroll
    for (int Mt = 0; Mt < 3; ++Mt)
        #pragma unroll
        for (int r = 0; r < 4; ++r) {
            float e = __expf(accB[Mt][r] - mx);
            accB[Mt][r] = e;
            sum += e;
        }
    sum += __shfl_xor(sum, 16);
    sum += __shfl_xor(sum, 32);
    float inv = 1.f / sum;
    #pragma unroll
    for (int Mt = 0; Mt < 3; ++Mt) {
        bf16x4 pv;
        #pragma unroll
        for (int r = 0; r < 4; ++r) {
            int s = 16 * Mt + 4 * g + r;
            float p = accB[Mt][r] * inv;
            wattn[((size_t)b * SL + s) * QQ + q] = p;
            pv[r] = f2bf(p);
        }
        int sbase = 16 * Mt + 4 * g;
        *(bf16x4*)(attq + w * 1024 + c * 64 + (sbase ^ ((c & 7) << 3))) = pv;
    }

    // ======== phase A: sv = (w_sv*sent) @ x, softmax over o ========
    const short* wsb = wsvS + (size_t)b * 16384;
    f32x4 accA[8];
    #pragma unroll
    for (int Mt = 0; Mt < 8; ++Mt) accA[Mt] = (f32x4){0.f, 0.f, 0.f, 0.f};
    #pragma unroll
    for (int Mt = 0; Mt < 8; ++Mt) {
        #pragma unroll
        for (int ks = 0; ks < 4; ++ks) {
            const bf16x8 wf = *(const bf16x8*)(wsb + (((Mt * 4 + ks) * 64 + l) * 8));
            accA[Mt] = __builtin_amdgcn_mfma_f32_16x16x32_bf16(wf, fxh[ks], accA[Mt], 0, 0, 0);
            accA[Mt] = __builtin_amdgcn_mfma_f32_16x16x32_bf16(wf, fxl[ks], accA[Mt], 0, 0, 0);
        }
    }
    float mA = -INFINITY;
    #pragma unroll
    for (int Mt = 0; Mt < 8; ++Mt)
        #pragma unroll
        for (int r = 0; r < 4; ++r) mA = fmaxf(mA, accA[Mt][r]);
    mA = fmaxf(mA, __shfl_xor(mA, 16));
    mA = fmaxf(mA, __shfl_xor(mA, 32));
    float sA = 0.f;
    #pragma unroll
    for (int Mt = 0; Mt < 8; ++Mt)
        #pragma unroll
        for (int r = 0; r < 4; ++r) {
            float e = __expf(accA[Mt][r] - mA);
            accA[Mt][r] = e;
            sA += e;
        }
    sA += __shfl_xor(sA, 16);
    sA += __shfl_xor(sA, 32);
    float invA = 1.f / sA;
    #pragma unroll
    for (int Mt = 0; Mt < 8; ++Mt)
        #pragma unroll
        for (int r = 0; r < 4; ++r) {
            int o = 16 * Mt + 4 * g + r;
            float p = accA[Mt][r] * invA;
            size_t off = ((size_t)b * IDF + o) * QQ + q;
            satt[off]  = p;
            wsent[off] = sent_lds[o] * p;
        }

    // ======== phase C: wctx = srcT @ attn ========
    // B-frag from attq (same-wave RAW, DS in-order): k(s) = 32*ks + 8*g + j
    bf16x8 fat[2];
    #pragma unroll
    for (int ks = 0; ks < 2; ++ks)
        fat[ks] = *(const bf16x8*)(attq + w * 1024 + c * 64 +
                                   ((32 * ks + 8 * g) ^ ((c & 7) << 3)));
    const short* stCb = stC + (size_t)b * 8192;
    #pragma unroll
    for (int Mt = 0; Mt < 8; ++Mt) {
        f32x4 a = {0.f, 0.f, 0.f, 0.f};
        #pragma unroll
        for (int ks = 0; ks < 2; ++ks) {
            const bf16x8 cf = *(const bf16x8*)(stCb + (((Mt * 2 + ks) * 64 + l) * 8));
            a = __builtin_amdgcn_mfma_f32_16x16x32_bf16(cf, fat[ks], a, 0, 0, 0);
        }
        #pragma unroll
        for (int r = 0; r < 4; ++r) {
            int i = 16 * Mt + 4 * g + r;
            wctx[((size_t)b * IDF + i) * QQ + q] = a[r];
        }
    }
}

extern "C" void kernel_launch(void* const* d_in, const int* in_sizes, int n_in,
                              void* d_out, int out_size, void* d_ws, size_t ws_size,
                              hipStream_t stream) {
    const float* input    = (const float*)d_in[0];
    const float* sentence = (const float*)d_in[1];
    const float* context  = (const float*)d_in[2];
    const int*   mask     = (const int*)d_in[3];
    const float* w_ctx    = (const float*)d_in[4];
    const float* w_sv     = (const float*)d_in[5];
    const float* w_lin    = (const float*)d_in[6];
    const float* b_lin    = (const float*)d_in[7];

    float* out = (float*)d_out;
    float* out_wctx  = out;
    float* out_wsent = out + (size_t)BB * IDF * QQ;
    float* out_wattn = out + 2 * (size_t)BB * IDF * QQ;
    float* out_satt  = out_wattn + (size_t)BB * SL * QQ;

    // ws layout: srcT f32 [16*128*48] | sent f32 [16*128] | bf16 frag arrays
    float* ws    = (float*)d_ws;
    float* srcT  = ws;                       // 98304 f
    float* sentW = ws + 98304;               // 2048 f
    short* wsvS  = (short*)(ws + 100352);    // 262144 h
    short* stB   = wsvS + 262144;            // 196608 h
    short* stC   = stB + 196608;             // 131072 h

    prep_kernel<<<dim3(16, 4), 256, 0, stream>>>(context, w_ctx, sentence,
                                                 w_lin, b_lin, srcT, sentW);
    prep2_kernel<<<dim3(16, 3), 256, 0, stream>>>(srcT, sentW, w_sv,
                                                  wsvS, stB, stC);
    fused_kernel<<<dim3(4096), 256, 0, stream>>>(input, stB, stC, wsvS, sentW,
                                                 mask, out_wctx, out_wsent,
                                                 out_wattn, out_satt);
}

// Round 9
// 177.512 us; speedup vs baseline: 5.9689x; 1.2884x over previous
//
#include <hip/hip_runtime.h>
#include <math.h>
#include <stdint.h>

#define BB  16
#define IDF 128
#define CDF 256
#define SL  48
#define QQ  16384   // 128*128
#define QT  64      // q-tile per block

typedef short bf16x8 __attribute__((ext_vector_type(8)));
typedef short bf16x4 __attribute__((ext_vector_type(4)));
typedef float f32x4  __attribute__((ext_vector_type(4)));

__device__ __forceinline__ short f2bf(float f) {
    uint32_t u = __builtin_bit_cast(uint32_t, f);
    u += 0x7FFFu + ((u >> 16) & 1u);          // RNE
    return (short)(u >> 16);
}
__device__ __forceinline__ float bf2f(short h) {
    uint32_t u = ((uint32_t)(unsigned short)h) << 16;
    return __builtin_bit_cast(float, u);
}

// ============ prepM: srcT via MFMA + direct frag-array emission ============
// One block per b. srcT = w_ctx @ context[b] ([128i][48s], K=256c), hi/lo x
// hi/lo (3 terms). D -> LDS tile -> emit stB/stC/wsvS frag arrays + sentW.
__global__ __launch_bounds__(256) void prepM_kernel(
    const float* __restrict__ context,   // [B][CDF][SL]
    const float* __restrict__ w_ctx,     // [IDF][CDF]
    const float* __restrict__ sentence,  // [B][100]
    const float* __restrict__ w_lin,     // [IDF][100]
    const float* __restrict__ b_lin,     // [IDF]
    const float* __restrict__ w_sv,      // [IDF o][IDF i]
    float* __restrict__ sentW,           // [B][IDF]
    short* __restrict__ wsvS,            // [B][8Mt][4ks][64][8]
    short* __restrict__ stB,             // [B][3Mt][4ks][2][64][8]
    short* __restrict__ stC)             // [B][8Mt][2ks][64][8]
{
    const int b = blockIdx.x;
    const int t = threadIdx.x;
    const int wv = t >> 6, l = t & 63;
    const int c = l & 15, g = l >> 4;

    __shared__ __align__(16) short ctxT_h[SL * CDF];   // 24 KB [s][c^swz] hi
    __shared__ __align__(16) short ctxT_l[SL * CDF];   // 24 KB lo
    __shared__ float srcTile[IDF * SL];                // 24 KB [i][s]
    __shared__ float sent_sh[IDF];

    // ---- sent (overlaps with staging latency) ----
    if (t < IDF) {
        float a = b_lin[t];
        for (int k = 0; k < 100; ++k)
            a += sentence[b * 100 + k] * w_lin[t * 100 + k];
        sent_sh[t] = a;
        sentW[b * IDF + t] = a;
    }

    // ---- stage context transposed hi/lo: 1536 tasks (128 c-pairs x 12 s4) ----
    for (int r = 0; r < 6; ++r) {
        int task = r * 256 + t;
        int cp = task & 127, s4 = task >> 7;       // cd pair, s4 group
        int cd = cp * 2, sb = s4 * 4;
        const float* row0 = context + ((size_t)b * CDF + cd) * SL + sb;
        const float4 va = *(const float4*)(row0);
        const float4 vb = *(const float4*)(row0 + SL);
        float va_[4] = {va.x, va.y, va.z, va.w};
        float vb_[4] = {vb.x, vb.y, vb.z, vb.w};
        #pragma unroll
        for (int j = 0; j < 4; ++j) {
            int s = sb + j;
            short h0 = f2bf(va_[j]), h1 = f2bf(vb_[j]);
            short l0 = f2bf(va_[j] - bf2f(h0)), l1 = f2bf(vb_[j] - bf2f(h1));
            int e = s * CDF + (cd ^ ((s & 15) << 3));
            *(uint32_t*)(ctxT_h + e) = (uint32_t)(uint16_t)h0 | ((uint32_t)(uint16_t)h1 << 16);
            *(uint32_t*)(ctxT_l + e) = (uint32_t)(uint16_t)l0 | ((uint32_t)(uint16_t)l1 << 16);
        }
    }
    __syncthreads();

    // ---- MFMA: wave wv owns Mt = 2wv, 2wv+1 (i-strips of 16) ----
    #pragma unroll
    for (int mi = 0; mi < 2; ++mi) {
        const int Mt = wv * 2 + mi;
        const int m = 16 * Mt + c;
        // A-frags from global w_ctx (hi/lo): k = 8g + 32ks + j
        bf16x8 Ah[8], Al[8];
        #pragma unroll
        for (int ks = 0; ks < 8; ++ks) {
            const float* wp = w_ctx + m * CDF + 8 * g + 32 * ks;
            const float4 f0 = *(const float4*)(wp);
            const float4 f1 = *(const float4*)(wp + 4);
            float fv[8] = {f0.x, f0.y, f0.z, f0.w, f1.x, f1.y, f1.z, f1.w};
            #pragma unroll
            for (int j = 0; j < 8; ++j) {
                short h = f2bf(fv[j]);
                Ah[ks][j] = h;
                Al[ks][j] = f2bf(fv[j] - bf2f(h));
            }
        }
        #pragma unroll
        for (int Nt = 0; Nt < 3; ++Nt) {
            const int s = 16 * Nt + c;
            f32x4 acc = {0.f, 0.f, 0.f, 0.f};
            #pragma unroll
            for (int ks = 0; ks < 8; ++ks) {
                int e = s * CDF + ((8 * g + 32 * ks) ^ ((s & 15) << 3));
                const bf16x8 Bh = *(const bf16x8*)(ctxT_h + e);
                const bf16x8 Bl = *(const bf16x8*)(ctxT_l + e);
                acc = __builtin_amdgcn_mfma_f32_16x16x32_bf16(Ah[ks], Bh, acc, 0, 0, 0);
                acc = __builtin_amdgcn_mfma_f32_16x16x32_bf16(Ah[ks], Bl, acc, 0, 0, 0);
                acc = __builtin_amdgcn_mfma_f32_16x16x32_bf16(Al[ks], Bh, acc, 0, 0, 0);
            }
            #pragma unroll
            for (int r = 0; r < 4; ++r)
                srcTile[(16 * Mt + 4 * g + r) * SL + s] = acc[r];
        }
    }
    __syncthreads();   // srcTile + sent_sh ready

    // ---- emit stB: [s as m][i as k] hi/lo ----
    #pragma unroll
    for (int cc = 0; cc < 3; ++cc) {
        int comb = wv * 3 + cc;               // 0..11
        int Mt = comb >> 2, ks = comb & 3;
        int s = c + 16 * Mt;
        int ib = 8 * g + 32 * ks;
        bf16x8 hv, lv;
        #pragma unroll
        for (int j = 0; j < 8; ++j) {
            float v = srcTile[(ib + j) * SL + s];
            short h = f2bf(v);
            hv[j] = h;
            lv[j] = f2bf(v - bf2f(h));
        }
        size_t base = (size_t)b * 12288 + (((Mt * 4 + ks) * 2) * 64 + l) * 8;
        *(bf16x8*)(stB + base) = hv;
        *(bf16x8*)(stB + base + 512) = lv;
    }
    // ---- emit stC: [i as m][s as k], s padded to 64 ----
    #pragma unroll
    for (int cc = 0; cc < 4; ++cc) {
        int comb = wv * 4 + cc;               // 0..15
        int Mt = comb >> 1, ks = comb & 1;
        int i = c + 16 * Mt;
        int sb = 8 * g + 32 * ks;
        bf16x8 v8;
        #pragma unroll
        for (int j = 0; j < 8; ++j) {
            int s = sb + j;
            v8[j] = (s < SL) ? f2bf(srcTile[i * SL + s]) : (short)0;
        }
        *(bf16x8*)(stC + (size_t)b * 8192 + ((Mt * 2 + ks) * 64 + l) * 8) = v8;
    }
    // ---- emit wsvS: w_sv * sent ----
    #pragma unroll
    for (int cc = 0; cc < 8; ++cc) {
        int comb = wv * 8 + cc;               // 0..31
        int Mt = comb >> 2, ks = comb & 3;
        int o = c + 16 * Mt;
        int ib = g * 8 + 32 * ks;
        bf16x8 outv;
        #pragma unroll
        for (int j = 0; j < 8; ++j)
            outv[j] = f2bf(w_sv[o * IDF + ib + j] * sent_sh[ib + j]);
        *(bf16x8*)(wsvS + (size_t)b * 16384 + ((Mt * 4 + ks) * 64 + l) * 8) = outv;
    }
}

// ===================== fused MFMA kernel =====================
// LDS: xqh/xql only (32.7 KB) -> 4 blocks/CU. attq aliases xql after the
// fx-frag loads (bar2). Phase A is hi-only.
__global__ __launch_bounds__(256, 4) void fused_kernel(
    const float* __restrict__ input,   // [B][IDF][Q]
    const short* __restrict__ stB,
    const short* __restrict__ stC,
    const short* __restrict__ wsvS,
    const float* __restrict__ sentW,   // [B][IDF]
    const int*   __restrict__ mask,    // [B][SL]
    float* __restrict__ wctx, float* __restrict__ wsent,
    float* __restrict__ wattn, float* __restrict__ satt)
{
    const int bid = blockIdx.x;           // 4096 = 16 b x 256 tiles
    const int b   = bid >> 8;
    const int q0  = (bid & 255) * QT;
    const int t   = threadIdx.x;
    const int w   = t >> 6;               // wave -> q-strip (16 q)
    const int l   = t & 63;
    const int c   = l & 15;
    const int g   = l >> 4;

    __shared__ __align__(16) short xqh[QT * IDF];    // 16 KB [q][i^swz] hi
    __shared__ __align__(16) short xql[QT * IDF];    // 16 KB lo; attq alias later
    __shared__ float sbias[SL];
    __shared__ float sent_lds[IDF];

    // ---- stage x transposed, hi/lo split ----
    {
        const int qb = (t & 15) * 4;
        #pragma unroll
        for (int r = 0; r < 4; ++r) {
            int i = (r * 16 + (t >> 4)) * 2;
            const float4 va = *(const float4*)(input + ((size_t)b * IDF + i    ) * QQ + q0 + qb);
            const float4 vb = *(const float4*)(input + ((size_t)b * IDF + i + 1) * QQ + q0 + qb);
            float va_[4] = {va.x, va.y, va.z, va.w};
            float vb_[4] = {vb.x, vb.y, vb.z, vb.w};
            #pragma unroll
            for (int jj = 0; jj < 4; ++jj) {
                int q = qb + jj;
                short h0 = f2bf(va_[jj]);
                short h1 = f2bf(vb_[jj]);
                short l0 = f2bf(va_[jj] - bf2f(h0));
                short l1 = f2bf(vb_[jj] - bf2f(h1));
                int e = q * IDF + (i ^ ((q & 15) << 3));   // i even -> e even
                *(uint32_t*)(xqh + e) = (uint32_t)(uint16_t)h0 | ((uint32_t)(uint16_t)h1 << 16);
                *(uint32_t*)(xql + e) = (uint32_t)(uint16_t)l0 | ((uint32_t)(uint16_t)l1 << 16);
            }
        }
    }
    if (t < SL)  sbias[t] = mask[b * SL + t] ? -INFINITY : 0.f;
    if (t < IDF) sent_lds[t] = sentW[b * IDF + t];
    __syncthreads();                                  // bar1

    // ---- x B-fragments: plain b128, k = 32*ks + 8*g + j, n(q-col) = c ----
    const int qrow = 16 * w + c;
    const short* xh_p = xqh + qrow * IDF;
    const short* xl_p = xql + qrow * IDF;
    bf16x8 fxh[4], fxl[4];
    #pragma unroll
    for (int ks = 0; ks < 4; ++ks) {
        int off = (32 * ks + 8 * g) ^ (c << 3);       // qrow&15 == c
        fxh[ks] = *(const bf16x8*)(xh_p + off);
        fxl[ks] = *(const bf16x8*)(xl_p + off);
    }
    __syncthreads();                                  // bar2: xql now reusable

    short* attq = xql;                                // alias [4 strips][16][64]
    {   // zero this wave's strip (pad rows s>=48 must read 0)
        bf16x8 z = {0, 0, 0, 0, 0, 0, 0, 0};
        *(bf16x8*)(attq + w * 1024 + l * 16) = z;
        *(bf16x8*)(attq + w * 1024 + l * 16 + 8) = z;
    }

    const int q = q0 + qrow;

    // ======== phase B: logits L[s][q] = srcT^T x (hi/lo split) ========
    const short* stBb = stB + (size_t)b * 12288;
    f32x4 accB[3];
    #pragma unroll
    for (int Mt = 0; Mt < 3; ++Mt) {
        f32x4 a = {0.f, 0.f, 0.f, 0.f};
        #pragma unroll
        for (int ks = 0; ks < 4; ++ks) {
            const bf16x8 sh = *(const bf16x8*)(stBb + ((((Mt * 4 + ks) * 2 + 0) * 64 + l) * 8));
            const bf16x8 sl = *(const bf16x8*)(stBb + ((((Mt * 4 + ks) * 2 + 1) * 64 + l) * 8));
            a = __builtin_amdgcn_mfma_f32_16x16x32_bf16(sh, fxh[ks], a, 0, 0, 0);
            a = __builtin_amdgcn_mfma_f32_16x16x32_bf16(sh, fxl[ks], a, 0, 0, 0);
            a = __builtin_amdgcn_mfma_f32_16x16x32_bf16(sl, fxh[ks], a, 0, 0, 0);
        }
        accB[Mt] = a;
    }

    // softmax over s per q
    float mx = -INFINITY;
    #pragma unroll
    for (int Mt = 0; Mt < 3; ++Mt)
        #pragma unroll
        for (int r = 0; r < 4; ++r) {
            int s = 16 * Mt + 4 * g + r;
            float lv = accB[Mt][r] + sbias[s];
            accB[Mt][r] = lv;
            mx = fmaxf(mx, lv);
        }
    mx = fmaxf(mx, __shfl_xor(mx, 16));
    mx = fmaxf(mx, __shfl_xor(mx, 32));
    float sum = 0.f;
    #pragma unroll
    for (int Mt = 0; Mt < 3; ++Mt)
        #pragma unroll
        for (int r = 0; r < 4; ++r) {
            float e = __expf(accB[Mt][r] - mx);
            accB[Mt][r] = e;
            sum += e;
        }
    sum += __shfl_xor(sum, 16);
    sum += __shfl_xor(sum, 32);
    float inv = 1.f / sum;
    #pragma unroll
    for (int Mt = 0; Mt < 3; ++Mt) {
        bf16x4 pv;
        #pragma unroll
        for (int r = 0; r < 4; ++r) {
            int s = 16 * Mt + 4 * g + r;
            float p = accB[Mt][r] * inv;
            wattn[((size_t)b * SL + s) * QQ + q] = p;
            pv[r] = f2bf(p);
        }
        int sbase = 16 * Mt + 4 * g;
        *(bf16x4*)(attq + w * 1024 + c * 64 + (sbase ^ ((c & 7) << 3))) = pv;
    }

    // ======== phase A: sv = (w_sv*sent) @ x (hi only), softmax over o ========
    const short* wsb = wsvS + (size_t)b * 16384;
    f32x4 accA[8];
    #pragma unroll
    for (int Mt = 0; Mt < 8; ++Mt) accA[Mt] = (f32x4){0.f, 0.f, 0.f, 0.f};
    #pragma unroll
    for (int Mt = 0; Mt < 8; ++Mt) {
        #pragma unroll
        for (int ks = 0; ks < 4; ++ks) {
            const bf16x8 wf = *(const bf16x8*)(wsb + (((Mt * 4 + ks) * 64 + l) * 8));
            accA[Mt] = __builtin_amdgcn_mfma_f32_16x16x32_bf16(wf, fxh[ks], accA[Mt], 0, 0, 0);
        }
    }
    float mA = -INFINITY;
    #pragma unroll
    for (int Mt = 0; Mt < 8; ++Mt)
        #pragma unroll
        for (int r = 0; r < 4; ++r) mA = fmaxf(mA, accA[Mt][r]);
    mA = fmaxf(mA, __shfl_xor(mA, 16));
    mA = fmaxf(mA, __shfl_xor(mA, 32));
    float sA = 0.f;
    #pragma unroll
    for (int Mt = 0; Mt < 8; ++Mt)
        #pragma unroll
        for (int r = 0; r < 4; ++r) {
            float e = __expf(accA[Mt][r] - mA);
            accA[Mt][r] = e;
            sA += e;
        }
    sA += __shfl_xor(sA, 16);
    sA += __shfl_xor(sA, 32);
    float invA = 1.f / sA;
    #pragma unroll
    for (int Mt = 0; Mt < 8; ++Mt)
        #pragma unroll
        for (int r = 0; r < 4; ++r) {
            int o = 16 * Mt + 4 * g + r;
            float p = accA[Mt][r] * invA;
            size_t off = ((size_t)b * IDF + o) * QQ + q;
            satt[off]  = p;
            wsent[off] = sent_lds[o] * p;
        }

    // ======== phase C: wctx = srcT @ attn (same-wave attq RAW) ========
    bf16x8 fat[2];
    #pragma unroll
    for (int ks = 0; ks < 2; ++ks)
        fat[ks] = *(const bf16x8*)(attq + w * 1024 + c * 64 +
                                   ((32 * ks + 8 * g) ^ ((c & 7) << 3)));
    const short* stCb = stC + (size_t)b * 8192;
    #pragma unroll
    for (int Mt = 0; Mt < 8; ++Mt) {
        f32x4 a = {0.f, 0.f, 0.f, 0.f};
        #pragma unroll
        for (int ks = 0; ks < 2; ++ks) {
            const bf16x8 cf = *(const bf16x8*)(stCb + (((Mt * 2 + ks) * 64 + l) * 8));
            a = __builtin_amdgcn_mfma_f32_16x16x32_bf16(cf, fat[ks], a, 0, 0, 0);
        }
        #pragma unroll
        for (int r = 0; r < 4; ++r) {
            int i = 16 * Mt + 4 * g + r;
            wctx[((size_t)b * IDF + i) * QQ + q] = a[r];
        }
    }
}

extern "C" void kernel_launch(void* const* d_in, const int* in_sizes, int n_in,
                              void* d_out, int out_size, void* d_ws, size_t ws_size,
                              hipStream_t stream) {
    const float* input    = (const float*)d_in[0];
    const float* sentence = (const float*)d_in[1];
    const float* context  = (const float*)d_in[2];
    const int*   mask     = (const int*)d_in[3];
    const float* w_ctx    = (const float*)d_in[4];
    const float* w_sv     = (const float*)d_in[5];
    const float* w_lin    = (const float*)d_in[6];
    const float* b_lin    = (const float*)d_in[7];

    float* out = (float*)d_out;
    float* out_wctx  = out;
    float* out_wsent = out + (size_t)BB * IDF * QQ;
    float* out_wattn = out + 2 * (size_t)BB * IDF * QQ;
    float* out_satt  = out_wattn + (size_t)BB * SL * QQ;

    // ws layout: sentW f32 [2048] | wsvS | stB | stC (bf16 frag arrays)
    float* ws    = (float*)d_ws;
    float* sentW = ws;                       // 2048 f
    short* wsvS  = (short*)(ws + 2048);      // 262144 h
    short* stB   = wsvS + 262144;            // 196608 h
    short* stC   = stB + 196608;             // 131072 h

    prepM_kernel<<<dim3(16), 256, 0, stream>>>(context, w_ctx, sentence,
                                               w_lin, b_lin, w_sv,
                                               sentW, wsvS, stB, stC);
    fused_kernel<<<dim3(4096), 256, 0, stream>>>(input, stB, stC, wsvS, sentW,
                                                 mask, out_wctx, out_wsent,
                                                 out_wattn, out_satt);
}

// Round 11
// 136.552 us; speedup vs baseline: 7.7594x; 1.3000x over previous
//
#include <hip/hip_runtime.h>
#include <math.h>
#include <stdint.h>

#define BB  16
#define IDF 128
#define CDF 256
#define SL  48
#define QQ  16384   // 128*128
#define QT  64      // q-tile per block

typedef short bf16x8 __attribute__((ext_vector_type(8)));
typedef short bf16x4 __attribute__((ext_vector_type(4)));
typedef float f32x4  __attribute__((ext_vector_type(4)));

__device__ __forceinline__ short f2bf(float f) {
    uint32_t u = __builtin_bit_cast(uint32_t, f);
    u += 0x7FFFu + ((u >> 16) & 1u);          // RNE
    return (short)(u >> 16);
}
__device__ __forceinline__ float bf2f(short h) {
    uint32_t u = ((uint32_t)(unsigned short)h) << 16;
    return __builtin_bit_cast(float, u);
}

// ============ prepM: srcT via MFMA + direct frag-array emission ============
__global__ __launch_bounds__(256) void prepM_kernel(
    const float* __restrict__ context,   // [B][CDF][SL]
    const float* __restrict__ w_ctx,     // [IDF][CDF]
    const float* __restrict__ sentence,  // [B][100]
    const float* __restrict__ w_lin,     // [IDF][100]
    const float* __restrict__ b_lin,     // [IDF]
    const float* __restrict__ w_sv,      // [IDF o][IDF i]
    float* __restrict__ sentW,           // [B][IDF]
    short* __restrict__ wsvS,            // [B][8Mt][4ks][64][8]
    short* __restrict__ stB,             // [B][3Mt][4ks][2][64][8]
    short* __restrict__ stC)             // [B][8Mt][2ks][64][8]
{
    const int b = blockIdx.x;
    const int t = threadIdx.x;
    const int wv = t >> 6, l = t & 63;
    const int c = l & 15, g = l >> 4;

    __shared__ __align__(16) short ctxT_h[SL * CDF];   // 24 KB [s][c^swz] hi
    __shared__ __align__(16) short ctxT_l[SL * CDF];   // 24 KB lo
    __shared__ float srcTile[IDF * SL];                // 24 KB [i][s]
    __shared__ float sent_sh[IDF];

    if (t < IDF) {
        float a = b_lin[t];
        for (int k = 0; k < 100; ++k)
            a += sentence[b * 100 + k] * w_lin[t * 100 + k];
        sent_sh[t] = a;
        sentW[b * IDF + t] = a;
    }

    for (int r = 0; r < 6; ++r) {
        int task = r * 256 + t;
        int cp = task & 127, s4 = task >> 7;
        int cd = cp * 2, sb = s4 * 4;
        const float* row0 = context + ((size_t)b * CDF + cd) * SL + sb;
        const float4 va = *(const float4*)(row0);
        const float4 vb = *(const float4*)(row0 + SL);
        float va_[4] = {va.x, va.y, va.z, va.w};
        float vb_[4] = {vb.x, vb.y, vb.z, vb.w};
        #pragma unroll
        for (int j = 0; j < 4; ++j) {
            int s = sb + j;
            short h0 = f2bf(va_[j]), h1 = f2bf(vb_[j]);
            short l0 = f2bf(va_[j] - bf2f(h0)), l1 = f2bf(vb_[j] - bf2f(h1));
            int e = s * CDF + (cd ^ ((s & 15) << 3));
            *(uint32_t*)(ctxT_h + e) = (uint32_t)(uint16_t)h0 | ((uint32_t)(uint16_t)h1 << 16);
            *(uint32_t*)(ctxT_l + e) = (uint32_t)(uint16_t)l0 | ((uint32_t)(uint16_t)l1 << 16);
        }
    }
    __syncthreads();

    #pragma unroll
    for (int mi = 0; mi < 2; ++mi) {
        const int Mt = wv * 2 + mi;
        const int m = 16 * Mt + c;
        bf16x8 Ah[8], Al[8];
        #pragma unroll
        for (int ks = 0; ks < 8; ++ks) {
            const float* wp = w_ctx + m * CDF + 8 * g + 32 * ks;
            const float4 f0 = *(const float4*)(wp);
            const float4 f1 = *(const float4*)(wp + 4);
            float fv[8] = {f0.x, f0.y, f0.z, f0.w, f1.x, f1.y, f1.z, f1.w};
            #pragma unroll
            for (int j = 0; j < 8; ++j) {
                short h = f2bf(fv[j]);
                Ah[ks][j] = h;
                Al[ks][j] = f2bf(fv[j] - bf2f(h));
            }
        }
        #pragma unroll
        for (int Nt = 0; Nt < 3; ++Nt) {
            const int s = 16 * Nt + c;
            f32x4 acc = {0.f, 0.f, 0.f, 0.f};
            #pragma unroll
            for (int ks = 0; ks < 8; ++ks) {
                int e = s * CDF + ((8 * g + 32 * ks) ^ ((s & 15) << 3));
                const bf16x8 Bh = *(const bf16x8*)(ctxT_h + e);
                const bf16x8 Bl = *(const bf16x8*)(ctxT_l + e);
                acc = __builtin_amdgcn_mfma_f32_16x16x32_bf16(Ah[ks], Bh, acc, 0, 0, 0);
                acc = __builtin_amdgcn_mfma_f32_16x16x32_bf16(Ah[ks], Bl, acc, 0, 0, 0);
                acc = __builtin_amdgcn_mfma_f32_16x16x32_bf16(Al[ks], Bh, acc, 0, 0, 0);
            }
            #pragma unroll
            for (int r = 0; r < 4; ++r)
                srcTile[(16 * Mt + 4 * g + r) * SL + s] = acc[r];
        }
    }
    __syncthreads();

    #pragma unroll
    for (int cc = 0; cc < 3; ++cc) {
        int comb = wv * 3 + cc;
        int Mt = comb >> 2, ks = comb & 3;
        int s = c + 16 * Mt;
        int ib = 8 * g + 32 * ks;
        bf16x8 hv, lv;
        #pragma unroll
        for (int j = 0; j < 8; ++j) {
            float v = srcTile[(ib + j) * SL + s];
            short h = f2bf(v);
            hv[j] = h;
            lv[j] = f2bf(v - bf2f(h));
        }
        size_t base = (size_t)b * 12288 + (((Mt * 4 + ks) * 2) * 64 + l) * 8;
        *(bf16x8*)(stB + base) = hv;
        *(bf16x8*)(stB + base + 512) = lv;
    }
    #pragma unroll
    for (int cc = 0; cc < 4; ++cc) {
        int comb = wv * 4 + cc;
        int Mt = comb >> 1, ks = comb & 1;
        int i = c + 16 * Mt;
        int sb = 8 * g + 32 * ks;
        bf16x8 v8;
        #pragma unroll
        for (int j = 0; j < 8; ++j) {
            int s = sb + j;
            v8[j] = (s < SL) ? f2bf(srcTile[i * SL + s]) : (short)0;
        }
        *(bf16x8*)(stC + (size_t)b * 8192 + ((Mt * 2 + ks) * 64 + l) * 8) = v8;
    }
    #pragma unroll
    for (int cc = 0; cc < 8; ++cc) {
        int comb = wv * 8 + cc;
        int Mt = comb >> 2, ks = comb & 3;
        int o = c + 16 * Mt;
        int ib = g * 8 + 32 * ks;
        bf16x8 outv;
        #pragma unroll
        for (int j = 0; j < 8; ++j)
            outv[j] = f2bf(w_sv[o * IDF + ib + j] * sent_sh[ib + j]);
        *(bf16x8*)(wsvS + (size_t)b * 16384 + ((Mt * 4 + ks) * 64 + l) * 8) = outv;
    }
}

// ===================== fused MFMA kernel =====================
// Outputs satt/wsent/wctx go through a [128][64] f32 LDS tile (aliasing the
// dead x staging) and are stored cooperatively as 16B vectors (4x256B
// segments per wave-instr vs 4x64B for per-lane dword). All output stores
// are nontemporal (453 MB streaming; keep L2 for frag arrays + input).
__global__ __launch_bounds__(256, 4) void fused_kernel(
    const float* __restrict__ input,   // [B][IDF][Q]
    const short* __restrict__ stB,
    const short* __restrict__ stC,
    const short* __restrict__ wsvS,
    const float* __restrict__ sentW,   // [B][IDF]
    const int*   __restrict__ mask,    // [B][SL]
    float* __restrict__ wctx, float* __restrict__ wsent,
    float* __restrict__ wattn, float* __restrict__ satt)
{
    const int bid = blockIdx.x;           // 4096 = 16 b x 256 tiles
    const int b   = bid >> 8;
    const int q0  = (bid & 255) * QT;
    const int t   = threadIdx.x;
    const int w   = t >> 6;               // wave -> q-strip (16 q)
    const int l   = t & 63;
    const int c   = l & 15;
    const int g   = l >> 4;

    __shared__ __align__(16) short xq[2 * QT * IDF];  // 32 KB; tile alias later
    __shared__ float sbias[SL];
    __shared__ float sent_lds[IDF];

    short* xqh = xq;
    short* xql = xq + QT * IDF;

    // ---- stage x transposed, hi/lo split ----
    {
        const int qb = (t & 15) * 4;
        #pragma unroll
        for (int r = 0; r < 4; ++r) {
            int i = (r * 16 + (t >> 4)) * 2;
            const float4 va = *(const float4*)(input + ((size_t)b * IDF + i    ) * QQ + q0 + qb);
            const float4 vb = *(const float4*)(input + ((size_t)b * IDF + i + 1) * QQ + q0 + qb);
            float va_[4] = {va.x, va.y, va.z, va.w};
            float vb_[4] = {vb.x, vb.y, vb.z, vb.w};
            #pragma unroll
            for (int jj = 0; jj < 4; ++jj) {
                int q = qb + jj;
                short h0 = f2bf(va_[jj]);
                short h1 = f2bf(vb_[jj]);
                short l0 = f2bf(va_[jj] - bf2f(h0));
                short l1 = f2bf(vb_[jj] - bf2f(h1));
                int e = q * IDF + (i ^ ((q & 15) << 3));   // i even -> e even
                *(uint32_t*)(xqh + e) = (uint32_t)(uint16_t)h0 | ((uint32_t)(uint16_t)h1 << 16);
                *(uint32_t*)(xql + e) = (uint32_t)(uint16_t)l0 | ((uint32_t)(uint16_t)l1 << 16);
            }
        }
    }
    if (t < SL)  sbias[t] = mask[b * SL + t] ? -INFINITY : 0.f;
    if (t < IDF) sent_lds[t] = sentW[b * IDF + t];
    __syncthreads();                                  // bar1

    // ---- x B-fragments: plain b128, k = 32*ks + 8*g + j, n(q-col) = c ----
    const int qrow = 16 * w + c;
    const short* xh_p = xqh + qrow * IDF;
    const short* xl_p = xql + qrow * IDF;
    bf16x8 fxh[4], fxl[4];
    #pragma unroll
    for (int ks = 0; ks < 4; ++ks) {
        int off = (32 * ks + 8 * g) ^ (c << 3);       // qrow&15 == c
        fxh[ks] = *(const bf16x8*)(xh_p + off);
        fxl[ks] = *(const bf16x8*)(xl_p + off);
    }
    __syncthreads();                                  // bar2: xql reusable

    short* attq = xql;                                // alias [4 strips][16][64]
    {   // zero this wave's strip (pad rows s>=48 must read 0)
        bf16x8 z = {0, 0, 0, 0, 0, 0, 0, 0};
        *(bf16x8*)(attq + w * 1024 + l * 16) = z;
        *(bf16x8*)(attq + w * 1024 + l * 16 + 8) = z;
    }

    const int q = q0 + qrow;

    // ======== phase B: logits L[s][q] = srcT^T x (hi/lo split) ========
    const short* stBb = stB + (size_t)b * 12288;
    f32x4 accB[3];
    #pragma unroll
    for (int Mt = 0; Mt < 3; ++Mt) {
        f32x4 a = {0.f, 0.f, 0.f, 0.f};
        #pragma unroll
        for (int ks = 0; ks < 4; ++ks) {
            const bf16x8 sh = *(const bf16x8*)(stBb + ((((Mt * 4 + ks) * 2 + 0) * 64 + l) * 8));
            const bf16x8 sl = *(const bf16x8*)(stBb + ((((Mt * 4 + ks) * 2 + 1) * 64 + l) * 8));
            a = __builtin_amdgcn_mfma_f32_16x16x32_bf16(sh, fxh[ks], a, 0, 0, 0);
            a = __builtin_amdgcn_mfma_f32_16x16x32_bf16(sh, fxl[ks], a, 0, 0, 0);
            a = __builtin_amdgcn_mfma_f32_16x16x32_bf16(sl, fxh[ks], a, 0, 0, 0);
        }
        accB[Mt] = a;
    }

    // softmax over s per q
    float mx = -INFINITY;
    #pragma unroll
    for (int Mt = 0; Mt < 3; ++Mt)
        #pragma unroll
        for (int r = 0; r < 4; ++r) {
            int s = 16 * Mt + 4 * g + r;
            float lv = accB[Mt][r] + sbias[s];
            accB[Mt][r] = lv;
            mx = fmaxf(mx, lv);
        }
    mx = fmaxf(mx, __shfl_xor(mx, 16));
    mx = fmaxf(mx, __shfl_xor(mx, 32));
    float sum = 0.f;
    #pragma unroll
    for (int Mt = 0; Mt < 3; ++Mt)
        #pragma unroll
        for (int r = 0; r < 4; ++r) {
            float e = __expf(accB[Mt][r] - mx);
            accB[Mt][r] = e;
            sum += e;
        }
    sum += __shfl_xor(sum, 16);
    sum += __shfl_xor(sum, 32);
    float inv = 1.f / sum;
    #pragma unroll
    for (int Mt = 0; Mt < 3; ++Mt) {
        bf16x4 pv;
        #pragma unroll
        for (int r = 0; r < 4; ++r) {
            int s = 16 * Mt + 4 * g + r;
            float p = accB[Mt][r] * inv;
            __builtin_nontemporal_store(p, wattn + ((size_t)b * SL + s) * QQ + q);
            pv[r] = f2bf(p);
        }
        int sbase = 16 * Mt + 4 * g;
        *(bf16x4*)(attq + w * 1024 + c * 64 + (sbase ^ ((c & 7) << 3))) = pv;
    }

    // ---- phase C B-frags NOW (attq region dies before tile aliasing) ----
    bf16x8 fat[2];
    #pragma unroll
    for (int ks = 0; ks < 2; ++ks)
        fat[ks] = *(const bf16x8*)(attq + w * 1024 + c * 64 +
                                   ((32 * ks + 8 * g) ^ ((c & 7) << 3)));

    // ======== phase A: sv = (w_sv*sent) @ x (hi only), softmax over o ========
    const short* wsb = wsvS + (size_t)b * 16384;
    f32x4 accA[8];
    #pragma unroll
    for (int Mt = 0; Mt < 8; ++Mt) accA[Mt] = (f32x4){0.f, 0.f, 0.f, 0.f};
    #pragma unroll
    for (int Mt = 0; Mt < 8; ++Mt) {
        #pragma unroll
        for (int ks = 0; ks < 4; ++ks) {
            const bf16x8 wf = *(const bf16x8*)(wsb + (((Mt * 4 + ks) * 64 + l) * 8));
            accA[Mt] = __builtin_amdgcn_mfma_f32_16x16x32_bf16(wf, fxh[ks], accA[Mt], 0, 0, 0);
        }
    }
    float mA = -INFINITY;
    #pragma unroll
    for (int Mt = 0; Mt < 8; ++Mt)
        #pragma unroll
        for (int r = 0; r < 4; ++r) mA = fmaxf(mA, accA[Mt][r]);
    mA = fmaxf(mA, __shfl_xor(mA, 16));
    mA = fmaxf(mA, __shfl_xor(mA, 32));
    float sA = 0.f;
    #pragma unroll
    for (int Mt = 0; Mt < 8; ++Mt)
        #pragma unroll
        for (int r = 0; r < 4; ++r) {
            float e = __expf(accA[Mt][r] - mA);
            accA[Mt][r] = e;
            sA += e;
        }
    sA += __shfl_xor(sA, 16);
    sA += __shfl_xor(sA, 32);
    float invA = 1.f / sA;

    float* tile = (float*)xq;                 // [128 o][64 q] f32, 32 KB
    __syncthreads();                          // bar3: all waves done with xq/attq

    #pragma unroll
    for (int Mt = 0; Mt < 8; ++Mt)
        #pragma unroll
        for (int r = 0; r < 4; ++r)
            tile[(16 * Mt + 4 * g + r) * 64 + qrow] = accA[Mt][r] * invA;
    __syncthreads();                          // bar4: tile ready

    // coop store satt + wsent (16B vectors, 4x256B segments per wave-instr)
    #pragma unroll
    for (int k = 0; k < 8; ++k) {
        int idx = k * 256 + t;                // float4 idx 0..2047
        int o = idx >> 4, q4 = idx & 15;
        f32x4 v = ((const f32x4*)tile)[idx];
        size_t base = ((size_t)b * IDF + o) * QQ + q0 + q4 * 4;
        __builtin_nontemporal_store(v, (f32x4*)(satt + base));
        float sc = sent_lds[o];
        f32x4 vs = v * sc;
        __builtin_nontemporal_store(vs, (f32x4*)(wsent + base));
    }

    // ======== phase C: wctx = srcT @ attn (overlaps coop-store drain) ========
    const short* stCb = stC + (size_t)b * 8192;
    f32x4 accC[8];
    #pragma unroll
    for (int Mt = 0; Mt < 8; ++Mt) {
        f32x4 a = {0.f, 0.f, 0.f, 0.f};
        #pragma unroll
        for (int ks = 0; ks < 2; ++ks) {
            const bf16x8 cf = *(const bf16x8*)(stCb + (((Mt * 2 + ks) * 64 + l) * 8));
            a = __builtin_amdgcn_mfma_f32_16x16x32_bf16(cf, fat[ks], a, 0, 0, 0);
        }
        accC[Mt] = a;
    }
    __syncthreads();                          // bar5: all tile reads done

    #pragma unroll
    for (int Mt = 0; Mt < 8; ++Mt)
        #pragma unroll
        for (int r = 0; r < 4; ++r)
            tile[(16 * Mt + 4 * g + r) * 64 + qrow] = accC[Mt][r];
    __syncthreads();                          // bar6: tile ready

    #pragma unroll
    for (int k = 0; k < 8; ++k) {
        int idx = k * 256 + t;
        int o = idx >> 4, q4 = idx & 15;
        f32x4 v = ((const f32x4*)tile)[idx];
        size_t base = ((size_t)b * IDF + o) * QQ + q0 + q4 * 4;
        __builtin_nontemporal_store(v, (f32x4*)(wctx + base));
    }
}

extern "C" void kernel_launch(void* const* d_in, const int* in_sizes, int n_in,
                              void* d_out, int out_size, void* d_ws, size_t ws_size,
                              hipStream_t stream) {
    const float* input    = (const float*)d_in[0];
    const float* sentence = (const float*)d_in[1];
    const float* context  = (const float*)d_in[2];
    const int*   mask     = (const int*)d_in[3];
    const float* w_ctx    = (const float*)d_in[4];
    const float* w_sv     = (const float*)d_in[5];
    const float* w_lin    = (const float*)d_in[6];
    const float* b_lin    = (const float*)d_in[7];

    float* out = (float*)d_out;
    float* out_wctx  = out;
    float* out_wsent = out + (size_t)BB * IDF * QQ;
    float* out_wattn = out + 2 * (size_t)BB * IDF * QQ;
    float* out_satt  = out_wattn + (size_t)BB * SL * QQ;

    float* ws    = (float*)d_ws;
    float* sentW = ws;                       // 2048 f
    short* wsvS  = (short*)(ws + 2048);      // 262144 h
    short* stB   = wsvS + 262144;            // 196608 h
    short* stC   = stB + 196608;             // 131072 h

    prepM_kernel<<<dim3(16), 256, 0, stream>>>(context, w_ctx, sentence,
                                               w_lin, b_lin, w_sv,
                                               sentW, wsvS, stB, stC);
    fused_kernel<<<dim3(4096), 256, 0, stream>>>(input, stB, stC, wsvS, sentW,
                                                 mask, out_wctx, out_wsent,
                                                 out_wattn, out_satt);
}